// Round 4
// baseline (153.311 us; speedup 1.0000x reference)
//
#include <hip/hip_runtime.h>
#include <math.h>

#define DIM   128
#define KCAP  1024   // dense cap for sub/obj indices
#define CW    2048   // AB row width: [0,KCAP)=sub coeffs, [KCAP,2*KCAP)=rel coeffs
#define EPG   20     // edges per 16-lane group in k_edge
#define EPB   (EPG * 16)
#define MT2   64     // M-tile rows per k_gemm2 block
#define KCH2  128    // K-chunk
#define NKC2  (CW / KCH2)   // 16

// ============ fused precompute: T, P1, P2, C4 (4 rows per wave) ============
__global__ void k_pre(const float* __restrict__ hidden, const float* __restrict__ rela,
                      const float* __restrict__ kg, const float* __restrict__ Ws,
                      const float* __restrict__ Wr, const float* __restrict__ Wh,
                      const float* __restrict__ Wkg, const float* __restrict__ Wkg_b,
                      float* __restrict__ P1, float* __restrict__ P2,
                      float* __restrict__ T, float* __restrict__ C4,
                      int MR, int n_rel, int NR2) {
  int wave = (blockIdx.x * blockDim.x + threadIdx.x) >> 6;
  int lane = threadIdx.x & 63;
  int jTh = (MR + 3) >> 2, jTr = (NR2 + 3) >> 2;
  int jP1 = (MR + 3) >> 2, jP2 = (n_rel + 3) >> 2;
  int j = wave;
  const float* IN; const float* W; float* OP; int rows;
  if (j < jTh) { IN = hidden; W = Wh; OP = T; rows = MR; }
  else if ((j -= jTh) < jTr) { IN = rela; W = Wh; OP = T + (size_t)KCAP * DIM; rows = NR2; }
  else if ((j -= jTr) < jP1) { IN = hidden; W = Ws; OP = P1; rows = MR; }
  else if ((j -= jP1) < jP2) { IN = rela; W = Wr; OP = P2; rows = n_rel; }
  else if ((j -= jP2) == 0) {
    // C4: all 4 rows in one wave
    float2 c0{0,0}, c1{0,0}, c2{0,0}, c3{0,0};
    const float2* W2 = (const float2*)Wkg;
#pragma unroll 2
    for (int k = 0; k < 2 * DIM; ++k) {
      float2 w = W2[k * 64 + lane];
      int kk = k & (DIM - 1);
      float v0 = kg[kk], v1 = kg[DIM + kk];
      float s01 = (k < DIM) ? v0 : v1;
      float s10 = (k < DIM) ? v1 : v0;
      c0.x += v0 * w.x;  c0.y += v0 * w.y;
      c1.x += s01 * w.x; c1.y += s01 * w.y;
      c2.x += s10 * w.x; c2.y += s10 * w.y;
      c3.x += v1 * w.x;  c3.y += v1 * w.y;
    }
    float2 b2 = ((const float2*)Wkg_b)[lane];
    c0.x += b2.x; c0.y += b2.y; c1.x += b2.x; c1.y += b2.y;
    c2.x += b2.x; c2.y += b2.y; c3.x += b2.x; c3.y += b2.y;
    ((float2*)(C4 + 0 * DIM))[lane] = c0;
    ((float2*)(C4 + 1 * DIM))[lane] = c1;
    ((float2*)(C4 + 2 * DIM))[lane] = c2;
    ((float2*)(C4 + 3 * DIM))[lane] = c3;
    return;
  } else return;
  int r0 = j * 4;
  int nv = rows - r0; if (nv > 4) nv = 4;
  const float* i0 = IN + (size_t)r0 * DIM;
  const float* i1 = IN + (size_t)(r0 + (nv > 1 ? 1 : 0)) * DIM;
  const float* i2 = IN + (size_t)(r0 + (nv > 2 ? 2 : 0)) * DIM;
  const float* i3 = IN + (size_t)(r0 + (nv > 3 ? 3 : 0)) * DIM;
  float2 a0{0,0}, a1{0,0}, a2{0,0}, a3{0,0};
  const float2* W2 = (const float2*)W;
#pragma unroll 4
  for (int k = 0; k < DIM; ++k) {
    float2 w = W2[k * 64 + lane];
    float v0 = i0[k], v1 = i1[k], v2 = i2[k], v3 = i3[k];
    a0.x += v0 * w.x; a0.y += v0 * w.y;
    a1.x += v1 * w.x; a1.y += v1 * w.y;
    a2.x += v2 * w.x; a2.y += v2 * w.y;
    a3.x += v3 * w.x; a3.y += v3 * w.y;
  }
  ((float2*)(OP + (size_t)r0 * DIM))[lane] = a0;
  if (nv > 1) ((float2*)(OP + (size_t)(r0 + 1) * DIM))[lane] = a1;
  if (nv > 2) ((float2*)(OP + (size_t)(r0 + 2) * DIM))[lane] = a2;
  if (nv > 3) ((float2*)(OP + (size_t)(r0 + 3) * DIM))[lane] = a3;
}

// ============ P2C[rel*4+c] = P2[rel] + C4[c] ============
__global__ void k_p2c(const float* __restrict__ P2, const float* __restrict__ C4,
                      float* __restrict__ P2C, int nr2) {
  int idx = blockIdx.x * blockDim.x + threadIdx.x;
  int total = nr2 * 4 * 32;
  if (idx >= total) return;
  int col = idx & 31;
  int row = idx >> 5;
  int c = row & 3, rel = row >> 2;
  float4 a = ((const float4*)P2)[rel * 32 + col];
  float4 b = ((const float4*)C4)[c * 32 + col];
  ((float4*)P2C)[idx] = make_float4(a.x + b.x, a.y + b.y, a.z + b.z, a.w + b.w);
}

// ============ per-edge alpha -> coefficient scatter ============
// LDS-staged edge ints + 2-deep gather pipeline, 16 lanes/edge.
__global__ __launch_bounds__(256, 4) void k_edge(
    const int* __restrict__ edges, int n_edge,
    const float* __restrict__ P1, const float* __restrict__ P2C,
    const float* __restrict__ w_alpha, const float* __restrict__ w_alpha_b,
    const int* __restrict__ left_ptr, float* __restrict__ AB,
    int* __restrict__ fb_list, int* __restrict__ fb_count, int mr, int nr2) {
  __shared__ int se[EPB * 6];
  int base = blockIdx.x * EPB;
  int cnt = n_edge - base; if (cnt > EPB) cnt = EPB;
  if (cnt <= 0) return;
  {
    const int* src = edges + (long long)base * 6;
    int tot = cnt * 6;
    int tot4 = tot >> 2;
    const int4* s4 = (const int4*)src;
    int4* d4 = (int4*)se;
    for (int i = threadIdx.x; i < tot4; i += 256) d4[i] = s4[i];
    for (int i = (tot4 << 2) + threadIdx.x; i < tot; i += 256) se[i] = src[i];
  }
  __syncthreads();
  int g = threadIdx.x >> 4;
  int l = threadIdx.x & 15;
  int left = left_ptr[0];
  float wb = w_alpha_b[0];
  const float4* wa4 = (const float4*)w_alpha;
  float4 wa0 = wa4[l * 2], wa1 = wa4[l * 2 + 1];

  int i0 = g * EPG;
  int iend = i0 + EPG; if (iend > cnt) iend = cnt;
  if (i0 >= iend) return;

  int relA, subA, objA; bool okA;
  float4 pa0A, pa1A, pb0A, pb1A;
  int relB, subB, objB; bool okB;
  float4 pa0B, pa1B, pb0B, pb1B;

#define LOADI(i, rel_, sub_, obj_, ok_, pa0_, pa1_, pb0_, pb1_)                 \
  {                                                                              \
    int hh = se[(i) * 6 + 1];                                                    \
    int2 rt = *(const int2*)&se[(i) * 6 + 2];                                    \
    int2 so = *(const int2*)&se[(i) * 6 + 4];                                    \
    rel_ = rt.x; sub_ = so.x; obj_ = so.y;                                       \
    ok_ = (sub_ < mr) && (obj_ < mr) && (rel_ < nr2);                            \
    if (ok_) {                                                                   \
      int c = ((hh >= left) ? 2 : 0) | ((rt.y >= left) ? 1 : 0);                 \
      const float4* p1 = (const float4*)(P1 + (long long)sub_ * DIM);            \
      const float4* p2 = (const float4*)(P2C + (long long)(rel_ * 4 + c) * DIM); \
      pa0_ = p1[l * 2]; pa1_ = p1[l * 2 + 1];                                    \
      pb0_ = p2[l * 2]; pb1_ = p2[l * 2 + 1];                                    \
    } else if (l == 0) {                                                         \
      int pos = atomicAdd(fb_count, 1);                                          \
      fb_list[pos] = base + (i);                                                 \
    }                                                                            \
  }

#define COMP(rel_, sub_, obj_, ok_, pa0_, pa1_, pb0_, pb1_)                      \
  if (ok_) {                                                                     \
    float s = fmaxf(pa0_.x + pb0_.x, 0.f) * wa0.x                                \
            + fmaxf(pa0_.y + pb0_.y, 0.f) * wa0.y                                \
            + fmaxf(pa0_.z + pb0_.z, 0.f) * wa0.z                                \
            + fmaxf(pa0_.w + pb0_.w, 0.f) * wa0.w                                \
            + fmaxf(pa1_.x + pb1_.x, 0.f) * wa1.x                                \
            + fmaxf(pa1_.y + pb1_.y, 0.f) * wa1.y                                \
            + fmaxf(pa1_.z + pb1_.z, 0.f) * wa1.z                                \
            + fmaxf(pa1_.w + pb1_.w, 0.f) * wa1.w;                               \
    s += __shfl_xor(s, 1); s += __shfl_xor(s, 2);                                \
    s += __shfl_xor(s, 4); s += __shfl_xor(s, 8);                                \
    if (l == 0) {                                                                \
      float alpha = 1.f / (1.f + expf(-(s + wb)));                               \
      atomicAdd(&AB[(long long)obj_ * CW + sub_], alpha);                        \
      atomicAdd(&AB[(long long)obj_ * CW + KCAP + rel_], alpha);                 \
    }                                                                            \
  }

  int icur = i0;
  LOADI(icur, relA, subA, objA, okA, pa0A, pa1A, pb0A, pb1A);
  for (;;) {
    int inext = icur + 1;
    bool hasNext = inext < iend;
    if (hasNext) LOADI(inext, relB, subB, objB, okB, pa0B, pa1B, pb0B, pb1B);
    COMP(relA, subA, objA, okA, pa0A, pa1A, pb0A, pb1A);
    if (!hasNext) break;
    icur = inext;
    int inn = icur + 1;
    bool h2 = inn < iend;
    if (h2) LOADI(inn, relA, subA, objA, okA, pa0A, pa1A, pb0A, pb1A);
    COMP(relB, subB, objB, okB, pa0B, pa1B, pb0B, pb1B);
    if (!h2) break;
    icur = inn;
  }
#undef LOADI
#undef COMP
}

// ============ split-K GEMM: part[kc][m][c] = AB[m][kc-chunk] @ T-chunk ============
__global__ __launch_bounds__(512) void k_gemm2(const float* __restrict__ AB,
                                               const float* __restrict__ T,
                                               float* __restrict__ part) {
  __shared__ float sh[MT2][KCH2 + 4];
  int mt = blockIdx.x / NKC2;
  int kc = blockIdx.x % NKC2;
  int m0 = mt * MT2, k0 = kc * KCH2;
  for (int i = threadIdx.x; i < MT2 * (KCH2 / 4); i += 512) {
    int r = i >> 5, kq = i & 31;
    *(float4*)&sh[r][kq * 4] = *(const float4*)(AB + (long long)(m0 + r) * CW + k0 + kq * 4);
  }
  __syncthreads();
  int cg = threadIdx.x & 31;   // cols cg*4..+3
  int rg = threadIdx.x >> 5;   // rows rg*4..+3
  const float4* T4 = (const float4*)T;
  float4 acc0 = {0,0,0,0}, acc1 = {0,0,0,0}, acc2 = {0,0,0,0}, acc3 = {0,0,0,0};
#pragma unroll 4
  for (int k = 0; k < KCH2; ++k) {
    float4 tv = T4[(long long)(k0 + k) * (DIM / 4) + cg];
    float a0 = sh[rg * 4 + 0][k];
    float a1 = sh[rg * 4 + 1][k];
    float a2 = sh[rg * 4 + 2][k];
    float a3 = sh[rg * 4 + 3][k];
    acc0.x += a0 * tv.x; acc0.y += a0 * tv.y; acc0.z += a0 * tv.z; acc0.w += a0 * tv.w;
    acc1.x += a1 * tv.x; acc1.y += a1 * tv.y; acc1.z += a1 * tv.z; acc1.w += a1 * tv.w;
    acc2.x += a2 * tv.x; acc2.y += a2 * tv.y; acc2.z += a2 * tv.z; acc2.w += a2 * tv.w;
    acc3.x += a3 * tv.x; acc3.y += a3 * tv.y; acc3.z += a3 * tv.z; acc3.w += a3 * tv.w;
  }
  float4* p = (float4*)(part + ((long long)kc * KCAP + m0 + rg * 4) * DIM) + cg;
  p[0 * (DIM / 4)] = acc0;
  p[1 * (DIM / 4)] = acc1;
  p[2 * (DIM / 4)] = acc2;
  p[3 * (DIM / 4)] = acc3;
}

// ============ reduce partials + zero tail -> out ============
__global__ void k_outfin(const float* __restrict__ part, float* __restrict__ out,
                         int n_node, int MR) {
  long long total = (long long)n_node * (DIM / 4);
  long long i = (long long)blockIdx.x * blockDim.x + threadIdx.x;
  long long stride = (long long)gridDim.x * blockDim.x;
  const float4* p4 = (const float4*)part;
  float4* o4 = (float4*)out;
  for (; i < total; i += stride) {
    long long r = i >> 5;
    int c4 = (int)(i & 31);
    float4 v = {0.f, 0.f, 0.f, 0.f};
    if (r < MR) {
#pragma unroll
      for (int kc = 0; kc < NKC2; ++kc) {
        float4 t = p4[((long long)kc * KCAP + r) * (DIM / 4) + c4];
        v.x += t.x; v.y += t.y; v.z += t.z; v.w += t.w;
      }
    }
    o4[i] = v;
  }
}

// ============ general fallback: one wave per listed edge, adds onto out ============
__global__ void k_fallback(const int* __restrict__ edges, const float* __restrict__ hidden,
                           const float* __restrict__ rela, const float* __restrict__ P2,
                           const float* __restrict__ C4, const float* __restrict__ Ws,
                           const float* __restrict__ w_alpha, const float* __restrict__ w_alpha_b,
                           const float* __restrict__ Wh, const int* __restrict__ left_ptr,
                           const int* __restrict__ fb_list, const int* __restrict__ fb_count,
                           float* __restrict__ out) {
  int nfb = fb_count[0];
  if (nfb == 0) return;
  int wave = (blockIdx.x * blockDim.x + threadIdx.x) >> 6;
  int nw = (gridDim.x * blockDim.x) >> 6;
  int lane = threadIdx.x & 63;
  int left = left_ptr[0];
  for (int i = wave; i < nfb; i += nw) {
    int e = fb_list[i];
    int head = edges[e * 6 + 1];
    int rel  = edges[e * 6 + 2];
    int tail = edges[e * 6 + 3];
    int sub  = edges[e * 6 + 4];
    int obj  = edges[e * 6 + 5];
    int c = ((head >= left) ? 2 : 0) | ((tail >= left) ? 1 : 0);
    float pre0 = P2[(long long)rel * DIM + lane] + C4[c * DIM + lane];
    float pre1 = P2[(long long)rel * DIM + 64 + lane] + C4[c * DIM + 64 + lane];
    for (int k = 0; k < DIM; ++k) {
      float h = hidden[(long long)sub * DIM + k];
      pre0 += h * Ws[k * DIM + lane];
      pre1 += h * Ws[k * DIM + 64 + lane];
    }
    float s = fmaxf(pre0, 0.f) * w_alpha[lane] + fmaxf(pre1, 0.f) * w_alpha[64 + lane];
    for (int d = 1; d < 64; d <<= 1) s += __shfl_xor(s, d);
    float alpha = 1.f / (1.f + expf(-(s + w_alpha_b[0])));
    float o0 = 0.f, o1 = 0.f;
    for (int k = 0; k < DIM; ++k) {
      float m = hidden[(long long)sub * DIM + k] + rela[(long long)rel * DIM + k];
      o0 += m * Wh[k * DIM + lane];
      o1 += m * Wh[k * DIM + 64 + lane];
    }
    atomicAdd(&out[(long long)obj * DIM + lane], alpha * o0);
    atomicAdd(&out[(long long)obj * DIM + 64 + lane], alpha * o1);
  }
}

extern "C" void kernel_launch(void* const* d_in, const int* in_sizes, int n_in,
                              void* d_out, int out_size, void* d_ws, size_t ws_size,
                              hipStream_t stream) {
  const float* hidden    = (const float*)d_in[0];
  const int*   edges     = (const int*)d_in[1];
  const float* kg_table  = (const float*)d_in[2];
  const float* rela      = (const float*)d_in[3];
  const float* Ws        = (const float*)d_in[4];
  const float* Wr        = (const float*)d_in[5];
  const float* Wkg_w     = (const float*)d_in[6];
  const float* Wkg_b     = (const float*)d_in[7];
  const float* w_alpha   = (const float*)d_in[8];
  const float* w_alpha_b = (const float*)d_in[9];
  const float* Wh        = (const float*)d_in[10];
  const int*   left_ptr  = (const int*)d_in[12];

  int n_node = out_size / DIM;
  int n_edge = in_sizes[1] / 6;
  int n_rel  = in_sizes[3] / DIM;
  int MR  = n_node < KCAP ? n_node : KCAP;
  int NR2 = n_rel < KCAP ? n_rel : KCAP;

  char* ws = (char*)d_ws;
  size_t o = 0;
  auto alloc = [&](size_t b) { size_t r = o; o += (b + 255) & ~(size_t)255; return r; };
  float* AB   = (float*)(ws + alloc((size_t)KCAP * CW * 4));           // 8 MB
  float* T    = (float*)(ws + alloc((size_t)CW * DIM * 4));            // 1 MB
  float* P1   = (float*)(ws + alloc((size_t)KCAP * DIM * 4));          // 512 KB
  float* P2   = (float*)(ws + alloc((size_t)n_rel * DIM * 4));
  float* C4   = (float*)(ws + alloc(4 * DIM * 4));
  float* P2C  = (float*)(ws + alloc((size_t)NR2 * 4 * DIM * 4));       // 2 MB
  float* part = (float*)(ws + alloc((size_t)NKC2 * KCAP * DIM * 4));   // 8 MB
  int*   fb_list  = (int*)(ws + alloc((size_t)n_edge * 4));
  int*   fb_count = (int*)(ws + alloc(4));
  float* out  = (float*)d_out;

  hipMemsetAsync(AB, 0, (size_t)KCAP * CW * 4, stream);
  hipMemsetAsync(fb_count, 0, 4, stream);
  if (MR < KCAP)
    hipMemsetAsync(T + (size_t)MR * DIM, 0, (size_t)(KCAP - MR) * DIM * 4, stream);
  if (NR2 < KCAP)
    hipMemsetAsync(T + (size_t)(KCAP + NR2) * DIM, 0, (size_t)(KCAP - NR2) * DIM * 4, stream);

  // fused precompute: T + P1 + P2 + C4 (4 rows per wave)
  int nj = ((MR + 3) >> 2) + ((NR2 + 3) >> 2) + ((MR + 3) >> 2) + ((n_rel + 3) >> 2) + 1;
  k_pre<<<(nj * 64 + 255) / 256, 256, 0, stream>>>(
      hidden, rela, kg_table, Ws, Wr, Wh, Wkg_w, Wkg_b, P1, P2, T, C4, MR, n_rel, NR2);

  // P2C = P2 + C4 (per (rel,c))
  k_p2c<<<(NR2 * 4 * 32 + 255) / 256, 256, 0, stream>>>(P2, C4, P2C, NR2);

  // per-edge alpha -> coefficient matrix
  int nb = (n_edge + EPB - 1) / EPB;
  k_edge<<<nb, 256, 0, stream>>>(edges, n_edge, P1, P2C, w_alpha, w_alpha_b,
                                 left_ptr, AB, fb_list, fb_count, MR, NR2);

  // split-K GEMM into partials, then fused reduce + zero-tail + out write
  k_gemm2<<<(KCAP / MT2) * NKC2, 512, 0, stream>>>(AB, T, part);
  k_outfin<<<4096, 256, 0, stream>>>(part, out, n_node, MR);

  // general-index fallback (empty for this dataset)
  k_fallback<<<64, 256, 0, stream>>>(edges, hidden, rela, P2, C4, Ws, w_alpha,
                                     w_alpha_b, Wh, left_ptr, fb_list, fb_count, out);
}